// Round 9
// baseline (18610.812 us; speedup 1.0000x reference)
//
#include <hip/hip_runtime.h>
#include <hip/hip_bf16.h>
#include <math.h>

#define T_STEPS 4096
#define IN_DIM  512
#define HID     2048
#define LEAK    0.3f

// ---------------------------------------------------------------------------
// Phase 1: P = U @ Win^T + bias, written directly into d_out (T x HID, f32)
// ---------------------------------------------------------------------------
#define GBM 64
#define GBN 64
#define GBK 32

__global__ __launch_bounds__(256) void gemm_p(const float* __restrict__ U,
                                              const float* __restrict__ Win,
                                              const float* __restrict__ bias,
                                              float* __restrict__ P) {
  __shared__ float As[GBM][GBK + 1];
  __shared__ float Bs[GBN][GBK + 1];
  const int bm = blockIdx.x, bn = blockIdx.y;
  const int tid = threadIdx.x;
  const int tx = tid & 15, ty = tid >> 4;

  float acc[4][4];
#pragma unroll
  for (int m = 0; m < 4; ++m)
#pragma unroll
    for (int n = 0; n < 4; ++n) acc[m][n] = 0.f;

  const float* Ub = U + (size_t)bm * GBM * IN_DIM;
  const float* Wb = Win + (size_t)bn * GBN * IN_DIM;

  for (int k0 = 0; k0 < IN_DIM; k0 += GBK) {
#pragma unroll
    for (int v = 0; v < 2; ++v) {
      const int f4 = v * 256 + tid;
      const int row = f4 >> 3;
      const int c4 = (f4 & 7) << 2;
      const float4 a = *(const float4*)(Ub + (size_t)row * IN_DIM + k0 + c4);
      As[row][c4 + 0] = a.x; As[row][c4 + 1] = a.y;
      As[row][c4 + 2] = a.z; As[row][c4 + 3] = a.w;
      const float4 b = *(const float4*)(Wb + (size_t)row * IN_DIM + k0 + c4);
      Bs[row][c4 + 0] = b.x; Bs[row][c4 + 1] = b.y;
      Bs[row][c4 + 2] = b.z; Bs[row][c4 + 3] = b.w;
    }
    __syncthreads();
#pragma unroll 8
    for (int k = 0; k < GBK; ++k) {
      float a[4], b[4];
#pragma unroll
      for (int m = 0; m < 4; ++m) a[m] = As[ty * 4 + m][k];
#pragma unroll
      for (int n = 0; n < 4; ++n) b[n] = Bs[tx * 4 + n][k];
#pragma unroll
      for (int m = 0; m < 4; ++m)
#pragma unroll
        for (int n = 0; n < 4; ++n)
          acc[m][n] = fmaf(a[m], b[n], acc[m][n]);
    }
    __syncthreads();
  }

#pragma unroll
  for (int m = 0; m < 4; ++m) {
    const int gr = bm * GBM + ty * 4 + m;
#pragma unroll
    for (int n = 0; n < 4; ++n) {
      const int gc = bn * GBN + tx * 4 + n;
      P[(size_t)gr * HID + gc] = acc[m][n] + bias[gc];
    }
  }
}

// ---------------------------------------------------------------------------
// Phase 2: persistent recurrence, DUAL-REDUNDANT tagged-word exchange.
//   Round-8 analysis: step = exchange (~2.3us) + compute (~0.4) + tail; the
//   exchange includes a per-step GLOBAL MAX over 128 producer publishes.
//   Fix: 2 groups x 128 blocks redundantly compute the full recurrence
//   (bit-identical f32 math); consumers accept each word from WHICHEVER
//   group published first -> per-word wait = min of two iid delays.
//   Laggards are now permitted (nobody waits on a redundant block), so:
//   - RING=8 slot buffers (lag tolerance ~6 steps).
//   - group A delays its out[t] store by 4 steps (register history, static
//     names) so group B's P_t = out[t] read can't race A's h_t overwrite
//     while lag < 4. B never writes out.
//   - W in LDS (round-7 structure; proven cost-equal, and avoids doubling
//     the per-XCD L2 working set to 4 MB with 32 blocks/XCD).
//   Protocol per word: h published as 64-bit {tag = t+1, f32 bits} via
//   relaxed AGENT-scope store; spin alternates A/B samples of word 0
//   (poll pressure ~flat); verify loads both groups' 8 words, merges
//   per-word. Double-buffered LDS h staging, one __syncthreads per step.
// ---------------------------------------------------------------------------
#define NB   256                 // 2 groups x 128 blocks
#define NGB  128                 // blocks per group
#define NT   256                 // threads per block
#define RPB  (HID / NGB)         // 16 rows per block
#define TPR  16                  // threads per row
#define NF4  (HID / (TPR * 4))   // 32 float4 chunks per thread-dot
#define WPT  (HID / NT)          // 8 exchanged words per thread
#define RING 8                   // slot ring depth per group

typedef unsigned long long ull;

__device__ __forceinline__ float fast_tanh(float x) {
  const float e = __expf(2.f * x);
  return 1.f - 2.f / (e + 1.f);
}

__device__ __forceinline__ void pub(ull* p, unsigned tag, float v) {
  const ull w = ((ull)tag << 32) | (ull)__float_as_uint(v);
  __hip_atomic_store(p, w, __ATOMIC_RELAXED, __HIP_MEMORY_SCOPE_AGENT);
}

__device__ __forceinline__ ull ald(const ull* p) {
  return __hip_atomic_load(p, __ATOMIC_RELAXED, __HIP_MEMORY_SCOPE_AGENT);
}

__global__ __launch_bounds__(NT, 1) void esn_recur(const float* __restrict__ W,
                                                   float* __restrict__ out,
                                                   ull* __restrict__ slots) {
  const int tid = threadIdx.x;
  const int j   = tid & (TPR - 1);       // lane within row
  const int rl  = tid >> 4;              // local row (0..15)
  const int grp = blockIdx.x >> 7;       // 0 = A (writes out), 1 = B (shadow)
  const int pb  = blockIdx.x & (NGB - 1);
  const int row = pb * RPB + rl;

  __shared__ float Wl[RPB][HID];         // 128 KB: this block's W rows
  __shared__ float hs[2][HID];           // 16 KB: double-buffered h staging

  // ---- prologue: stage W slice into LDS (one-time; ordered by the t=1
  //      staging barrier before first use) ----
  {
    const float4* wsrc = (const float4*)(W + (size_t)pb * RPB * HID);
    float4* wdst = (float4*)&Wl[0][0];
#pragma unroll 4
    for (int f = tid; f < RPB * HID / 4; f += NT) wdst[f] = wsrc[f];
  }

  // hist of last 4 h values (A only; static names -- no runtime indexing)
  float hp = 0.f, g0 = 0.f, g1 = 0.f, g2 = 0.f, g3 = 0.f;

  // ---- t = 0 (group A only): h0 = leak * tanh(P0), publish tag 1, ring 0.
  //      B stays silent (consumers fall back to A's words); B recovers
  //      hp = h0[row] from the t=1 LDS stage. ----
  if (grp == 0) {
    hp = LEAK * fast_tanh(out[row]);     // all 16 lanes of a row identical
    if (j == 0) pub(&slots[(size_t)0 * HID + row], 1u, hp);
    g0 = hp;
  }

  for (int t = 1; t < T_STEPS; ++t) {
    // ---- A: delayed out write (h_{t-4}); keeps out[t] = P_t readable by
    //      B until A is 4 steps past it ----
    if (grp == 0 && j == 0 && t >= 4)
      out[(size_t)(t - 4) * HID + row] = g3;
    g3 = g2; g2 = g1; g1 = g0;           // shift history

    const float p = out[(size_t)t * HID + row];  // P_t (safe while lag < 4)

    // ---- spin: alternate A/B samples of word 0 of my 8-word group ----
    const ull* __restrict__ sA =
        slots + (size_t)((t - 1) & (RING - 1)) * HID + (size_t)tid * WPT;
    const ull* __restrict__ sB = sA + (size_t)RING * HID;
    const unsigned tg = (unsigned)t;     // tag of h_{t-1}
    for (;;) {
      ull w0 = ald(sA);
      if ((unsigned)(w0 >> 32) == tg) break;
      w0 = ald(sB);
      if ((unsigned)(w0 >> 32) == tg) break;
    }

    // ---- verify: load both groups' 8 words, merge per-word ----
    ull wv[WPT];
    bool ok;
    do {
      ull wa[WPT], wb[WPT];
#pragma unroll
      for (int q = 0; q < WPT; ++q) wa[q] = ald(sA + q);
#pragma unroll
      for (int q = 0; q < WPT; ++q) wb[q] = ald(sB + q);
      ok = true;
#pragma unroll
      for (int q = 0; q < WPT; ++q) {
        const bool ga = ((unsigned)(wa[q] >> 32) == tg);
        const bool gb = ((unsigned)(wb[q] >> 32) == tg);
        wv[q] = ga ? wa[q] : wb[q];
        ok = ok && (ga || gb);
      }
    } while (!ok);

    float* __restrict__ hb = hs[(t - 1) & 1];
    float4 v0, v1;
    v0.x = __uint_as_float((unsigned)wv[0]);
    v0.y = __uint_as_float((unsigned)wv[1]);
    v0.z = __uint_as_float((unsigned)wv[2]);
    v0.w = __uint_as_float((unsigned)wv[3]);
    v1.x = __uint_as_float((unsigned)wv[4]);
    v1.y = __uint_as_float((unsigned)wv[5]);
    v1.z = __uint_as_float((unsigned)wv[6]);
    v1.w = __uint_as_float((unsigned)wv[7]);
    *(float4*)&hb[tid * WPT]     = v0;
    *(float4*)&hb[tid * WPT + 4] = v1;
    __syncthreads();                     // h_{t-1} staged (single barrier)

    if (grp == 1 && t == 1) hp = hb[row];  // B recovers h0[row]

    // ---- compute: dot(W[row], h), both operands from LDS ----
    const float* __restrict__ wl = &Wl[rl][0];
    float4 acc = make_float4(0.f, 0.f, 0.f, 0.f);
#pragma unroll
    for (int i = 0; i < NF4; ++i) {
      const int idx = (i * TPR + j) * 4;
      const float4 wvv = *(const float4*)&wl[idx];
      const float4 hv  = *(const float4*)&hb[idx];
      acc.x = fmaf(wvv.x, hv.x, acc.x);
      acc.y = fmaf(wvv.y, hv.y, acc.y);
      acc.z = fmaf(wvv.z, hv.z, acc.z);
      acc.w = fmaf(wvv.w, hv.w, acc.w);
    }
    float a = (acc.x + acc.y) + (acc.z + acc.w);
    a += __shfl_xor(a, 1, TPR);
    a += __shfl_xor(a, 2, TPR);
    a += __shfl_xor(a, 4, TPR);
    a += __shfl_xor(a, 8, TPR);          // all 16 lanes hold the full dot

    const float h = (1.f - LEAK) * hp + LEAK * fast_tanh(p + a);
    hp = h;
    g0 = h;
    if (j == 0)
      pub(&slots[(size_t)(grp * RING + (t & (RING - 1))) * HID + row],
          (unsigned)(t + 1), h);
  }

  // ---- epilogue: A drains the last 4 delayed out rows ----
  if (grp == 0 && j == 0) {
    out[(size_t)(T_STEPS - 4) * HID + row] = g3;
    out[(size_t)(T_STEPS - 3) * HID + row] = g2;
    out[(size_t)(T_STEPS - 2) * HID + row] = g1;
    out[(size_t)(T_STEPS - 1) * HID + row] = g0;
  }
}

// ---------------------------------------------------------------------------
extern "C" void kernel_launch(void* const* d_in, const int* in_sizes, int n_in,
                              void* d_out, int out_size, void* d_ws, size_t ws_size,
                              hipStream_t stream) {
  const float* U    = (const float*)d_in[0];
  const float* Win  = (const float*)d_in[1];
  const float* W    = (const float*)d_in[2];
  const float* bias = (const float*)d_in[3];
  float* out = (float*)d_out;
  ull* slots = (ull*)d_ws;

  // wipe all 2 groups x 8 rings of tags (tag 0 never valid; also clears
  // stale tags between graph replays)
  hipMemsetAsync(d_ws, 0, (size_t)2 * RING * HID * sizeof(ull), stream);

  dim3 ggrid(T_STEPS / GBM, HID / GBN);
  gemm_p<<<ggrid, 256, 0, stream>>>(U, Win, bias, out);

  esn_recur<<<NB, NT, 0, stream>>>(W, out, slots);
}

// Round 10
// 11471.402 us; speedup vs baseline: 1.6224x; 1.6224x over previous
//
#include <hip/hip_runtime.h>
#include <hip/hip_bf16.h>
#include <math.h>

#define T_STEPS 4096
#define IN_DIM  512
#define HID     2048
#define LEAK    0.3f

// ---------------------------------------------------------------------------
// Phase 1: P = U @ Win^T + bias, written directly into d_out (T x HID, f32)
// ---------------------------------------------------------------------------
#define GBM 64
#define GBN 64
#define GBK 32

__global__ __launch_bounds__(256) void gemm_p(const float* __restrict__ U,
                                              const float* __restrict__ Win,
                                              const float* __restrict__ bias,
                                              float* __restrict__ P) {
  __shared__ float As[GBM][GBK + 1];
  __shared__ float Bs[GBN][GBK + 1];
  const int bm = blockIdx.x, bn = blockIdx.y;
  const int tid = threadIdx.x;
  const int tx = tid & 15, ty = tid >> 4;

  float acc[4][4];
#pragma unroll
  for (int m = 0; m < 4; ++m)
#pragma unroll
    for (int n = 0; n < 4; ++n) acc[m][n] = 0.f;

  const float* Ub = U + (size_t)bm * GBM * IN_DIM;
  const float* Wb = Win + (size_t)bn * GBN * IN_DIM;

  for (int k0 = 0; k0 < IN_DIM; k0 += GBK) {
#pragma unroll
    for (int v = 0; v < 2; ++v) {
      const int f4 = v * 256 + tid;
      const int row = f4 >> 3;
      const int c4 = (f4 & 7) << 2;
      const float4 a = *(const float4*)(Ub + (size_t)row * IN_DIM + k0 + c4);
      As[row][c4 + 0] = a.x; As[row][c4 + 1] = a.y;
      As[row][c4 + 2] = a.z; As[row][c4 + 3] = a.w;
      const float4 b = *(const float4*)(Wb + (size_t)row * IN_DIM + k0 + c4);
      Bs[row][c4 + 0] = b.x; Bs[row][c4 + 1] = b.y;
      Bs[row][c4 + 2] = b.z; Bs[row][c4 + 3] = b.w;
    }
    __syncthreads();
#pragma unroll 8
    for (int k = 0; k < GBK; ++k) {
      float a[4], b[4];
#pragma unroll
      for (int m = 0; m < 4; ++m) a[m] = As[ty * 4 + m][k];
#pragma unroll
      for (int n = 0; n < 4; ++n) b[n] = Bs[tx * 4 + n][k];
#pragma unroll
      for (int m = 0; m < 4; ++m)
#pragma unroll
        for (int n = 0; n < 4; ++n)
          acc[m][n] = fmaf(a[m], b[n], acc[m][n]);
    }
    __syncthreads();
  }

#pragma unroll
  for (int m = 0; m < 4; ++m) {
    const int gr = bm * GBM + ty * 4 + m;
#pragma unroll
    for (int n = 0; n < 4; ++n) {
      const int gc = bn * GBN + tx * 4 + n;
      P[(size_t)gr * HID + gc] = acc[m][n] + bias[gc];
    }
  }
}

// ---------------------------------------------------------------------------
// Phase 2: persistent recurrence, tagged-word exchange, TWO-CHUNK PIPELINE.
//   Protocol = round-8 winner (single-hop tagged words, serial spin):
//   - h published as 64-bit {tag = t+1, f32 bits}, relaxed AGENT-scope
//     atomic store (bypasses non-coherent XCD L2); detect IS data arrival.
//   - ring-2 slot buffers (induction: a slot is only overwritten after all
//     its readers provably advanced).
//   NEW: h split into C0 = rows 0..1023, C1 = rows 1024..2047.
//     spin on C0 word0 -> issue C1's 4 loads SPECULATIVELY -> verify C0 ->
//     stage C0, barrier -> compute i=0..15 -> check in-flight C1 values
//     (tags almost surely current by now; rare re-poll otherwise) ->
//     stage C1, barrier -> compute i=16..31 -> reduce/publish.
//   C1's detect+verify latency hides under C0's verify+compute; added
//   fabric traffic ~zero (round 6/9 law: traffic and hops are poison).
//   W streams from XCD L2 (round 7/8: source of W is off critical path).
// ---------------------------------------------------------------------------
#define NB   128                 // blocks
#define NT   256                 // threads per block
#define RPB  (HID / NB)          // 16 rows per block
#define TPR  16                  // threads per row
#define NF4  (HID / (TPR * 4))   // 32 float4 chunks per thread-dot
#define HALF (HID / 2)           // 1024: chunk boundary

typedef unsigned long long ull;

__device__ __forceinline__ float fast_tanh(float x) {
  const float e = __expf(2.f * x);
  return 1.f - 2.f / (e + 1.f);
}

__device__ __forceinline__ void pub(ull* p, unsigned tag, float v) {
  const ull w = ((ull)tag << 32) | (ull)__float_as_uint(v);
  __hip_atomic_store(p, w, __ATOMIC_RELAXED, __HIP_MEMORY_SCOPE_AGENT);
}

__device__ __forceinline__ ull ald(const ull* p) {
  return __hip_atomic_load(p, __ATOMIC_RELAXED, __HIP_MEMORY_SCOPE_AGENT);
}

__global__ __launch_bounds__(NT, 1) void esn_recur(const float* __restrict__ W,
                                                   float* __restrict__ out,
                                                   ull* __restrict__ slots) {
  const int tid = threadIdx.x;
  const int j   = tid & (TPR - 1);       // lane within row
  const int rl  = tid >> 4;              // local row (0..15)
  const int row = blockIdx.x * RPB + rl;

  __shared__ float hs[2][HID];           // 16 KB: double-buffered h staging

  const float4* wrow = (const float4*)(W + (size_t)row * HID);

  // ---- t = 0: h0 = leak * tanh(P0), publish with tag 1 into ring 0 ----
  float hp = LEAK * fast_tanh(out[row]); // all 16 lanes of a row identical
  if (j == 0) {
    pub(&slots[row], 1u, hp);
    out[row] = hp;
  }

  for (int t = 1; t < T_STEPS; ++t) {
    float* __restrict__ ocur = out + (size_t)t * HID;
    const float p = ocur[row];           // issued early; drains at barrier 1

    const ull* __restrict__ s0 =
        slots + (size_t)((t - 1) & 1) * HID + (size_t)tid * 4;   // C0 words
    const ull* __restrict__ s1 = s0 + HALF;                      // C1 words
    const unsigned tg = (unsigned)t;     // tag of h_{t-1}

    // ---- spin on C0 word 0 (one outstanding poll load) ----
    ull a0;
    do {
      a0 = ald(s0);
    } while ((unsigned)(a0 >> 32) != tg);

    // ---- speculative C1 loads: in flight under C0 verify + compute0 ----
    ull c0 = ald(s1 + 0);
    ull c1 = ald(s1 + 1);
    ull c2 = ald(s1 + 2);
    ull c3 = ald(s1 + 3);

    // ---- verify C0 words 1..3 ----
    ull a1, a2, a3;
    bool ok;
    do {
      a1 = ald(s0 + 1); a2 = ald(s0 + 2); a3 = ald(s0 + 3);
      ok = ((unsigned)(a1 >> 32) == tg) &&
           ((unsigned)(a2 >> 32) == tg) &&
           ((unsigned)(a3 >> 32) == tg);
    } while (!ok);

    float* __restrict__ hb = hs[(t - 1) & 1];
    {
      float4 v;
      v.x = __uint_as_float((unsigned)a0);
      v.y = __uint_as_float((unsigned)a1);
      v.z = __uint_as_float((unsigned)a2);
      v.w = __uint_as_float((unsigned)a3);
      *(float4*)&hb[tid * 4] = v;
    }
    __syncthreads();                     // C0 staged (drains C1 loads too)

    // ---- compute chunk 0: i = 0..15 (h[0..1023]) ----
    float4 acc = make_float4(0.f, 0.f, 0.f, 0.f);
#pragma unroll
    for (int i = 0; i < NF4 / 2; ++i) {
      const int idx = (i * TPR + j) * 4;
      const float4 wv = wrow[i * TPR + j];
      const float4 hv = *(const float4*)&hb[idx];
      acc.x = fmaf(wv.x, hv.x, acc.x);
      acc.y = fmaf(wv.y, hv.y, acc.y);
      acc.z = fmaf(wv.z, hv.z, acc.z);
      acc.w = fmaf(wv.w, hv.w, acc.w);
    }

    // ---- C1: check speculative values; rare re-poll if stale ----
    while (!(((unsigned)(c0 >> 32) == tg) && ((unsigned)(c1 >> 32) == tg) &&
             ((unsigned)(c2 >> 32) == tg) && ((unsigned)(c3 >> 32) == tg))) {
      c0 = ald(s1 + 0); c1 = ald(s1 + 1);
      c2 = ald(s1 + 2); c3 = ald(s1 + 3);
    }
    {
      float4 v;
      v.x = __uint_as_float((unsigned)c0);
      v.y = __uint_as_float((unsigned)c1);
      v.z = __uint_as_float((unsigned)c2);
      v.w = __uint_as_float((unsigned)c3);
      *(float4*)&hb[HALF + tid * 4] = v;
    }
    __syncthreads();                     // C1 staged

    // ---- compute chunk 1: i = 16..31 (h[1024..2047]) ----
#pragma unroll
    for (int i = NF4 / 2; i < NF4; ++i) {
      const int idx = (i * TPR + j) * 4;
      const float4 wv = wrow[i * TPR + j];
      const float4 hv = *(const float4*)&hb[idx];
      acc.x = fmaf(wv.x, hv.x, acc.x);
      acc.y = fmaf(wv.y, hv.y, acc.y);
      acc.z = fmaf(wv.z, hv.z, acc.z);
      acc.w = fmaf(wv.w, hv.w, acc.w);
    }
    float a = (acc.x + acc.y) + (acc.z + acc.w);
    a += __shfl_xor(a, 1, TPR);
    a += __shfl_xor(a, 2, TPR);
    a += __shfl_xor(a, 4, TPR);
    a += __shfl_xor(a, 8, TPR);          // all 16 lanes hold the full dot

    const float h = (1.f - LEAK) * hp + LEAK * fast_tanh(p + a);
    hp = h;
    if (j == 0) {
      pub(&slots[(size_t)(t & 1) * HID + row], (unsigned)(t + 1), h);
      ocur[row] = h;                     // plain cached store (own column)
    }
  }
}

// ---------------------------------------------------------------------------
extern "C" void kernel_launch(void* const* d_in, const int* in_sizes, int n_in,
                              void* d_out, int out_size, void* d_ws, size_t ws_size,
                              hipStream_t stream) {
  const float* U    = (const float*)d_in[0];
  const float* Win  = (const float*)d_in[1];
  const float* W    = (const float*)d_in[2];
  const float* bias = (const float*)d_in[3];
  float* out = (float*)d_out;
  ull* slots = (ull*)d_ws;

  // wipe tags (also clears stale tags between graph replays); tag 0 is
  // never a valid tag (tags are t+1 >= 1), so memset can't false-match
  hipMemsetAsync(d_ws, 0, 2 * HID * sizeof(ull), stream);

  dim3 ggrid(T_STEPS / GBM, HID / GBN);
  gemm_p<<<ggrid, 256, 0, stream>>>(U, Win, bias, out);

  esn_recur<<<NB, NT, 0, stream>>>(W, out, slots);
}